// Round 9
// baseline (170.305 us; speedup 1.0000x reference)
//
#include <hip/hip_runtime.h>

#define Bsz 256
#define Dd  4096
#define MAXR 15
#define FMAX 3.402823466e+38f
#define BK 64

typedef short bf16x8 __attribute__((ext_vector_type(8)));
typedef float f32x4  __attribute__((ext_vector_type(4)));

__device__ __forceinline__ unsigned short f2bf(float f) {
    unsigned int u = __float_as_uint(f);
    unsigned int r = (u + 0x7fffu + ((u >> 16) & 1u)) >> 16;   // RNE
    return (unsigned short)r;
}
__device__ __forceinline__ float bf2f(unsigned short h) {
    return __uint_as_float(((unsigned int)h) << 16);
}

// async global->LDS, 16B per lane (dest = wave-uniform base + lane*16; size must be literal)
#define GLOAD16(gp, lp) __builtin_amdgcn_global_load_lds(                     \
    (const __attribute__((address_space(1))) void*)(gp),                      \
    (__attribute__((address_space(3))) void*)(lp), 16, 0, 0)

// ---- Kernel 1: S = 0.5*(W+W^T) -> bf16 hi/lo (triangle-paired) + fused x->bf16 ----
__global__ __launch_bounds__(256) void k_ssym(const float* __restrict__ W,
                                              const float* __restrict__ x,
                                              unsigned short* __restrict__ shi,
                                              unsigned short* __restrict__ slo,
                                              unsigned short* __restrict__ xb) {
    __shared__ float t1[64][68];
    __shared__ float t2[64][68];
    int bid = blockIdx.x;
    int bi = 0;
    while (bid >= 64 - bi) { bid -= 64 - bi; ++bi; }
    const int bj = bi + bid;
    const int i0 = bi * 64, j0 = bj * 64;
    const int tid = threadIdx.x;

    #pragma unroll
    for (int sb = 0; sb < 4; ++sb) {
        int s = sb * 256 + tid;
        int r = s >> 4, q = (s & 15) * 4;
        *(float4*)&t1[r][q] = *(const float4*)(W + (size_t)(i0 + r) * Dd + j0 + q);
        *(float4*)&t2[r][q] = *(const float4*)(W + (size_t)(j0 + r) * Dd + i0 + q);
    }
    __syncthreads();

    const int r = tid >> 2, c0 = (tid & 3) * 16;
    {   // S_ij[r][c] = 0.5*(t1[r][c] + t2[c][r])
        unsigned short vh[16], vl[16];
        #pragma unroll
        for (int k = 0; k < 16; ++k) {
            float s = 0.5f * (t1[r][c0 + k] + t2[c0 + k][r]);
            vh[k] = f2bf(s);
            vl[k] = f2bf(s - bf2f(vh[k]));
        }
        size_t o = (size_t)(i0 + r) * Dd + j0 + c0;
        *(uint4*)(shi + o) = *(const uint4*)&vh[0];
        *(uint4*)(shi + o + 8) = *(const uint4*)&vh[8];
        *(uint4*)(slo + o) = *(const uint4*)&vl[0];
        *(uint4*)(slo + o + 8) = *(const uint4*)&vl[8];
    }
    if (bi != bj) {   // S_ji[r][c] = 0.5*(t2[r][c] + t1[c][r])
        unsigned short vh[16], vl[16];
        #pragma unroll
        for (int k = 0; k < 16; ++k) {
            float s = 0.5f * (t2[r][c0 + k] + t1[c0 + k][r]);
            vh[k] = f2bf(s);
            vl[k] = f2bf(s - bf2f(vh[k]));
        }
        size_t o = (size_t)(j0 + r) * Dd + i0 + c0;
        *(uint4*)(shi + o) = *(const uint4*)&vh[0];
        *(uint4*)(shi + o + 8) = *(const uint4*)&vh[8];
        *(uint4*)(slo + o) = *(const uint4*)&vl[0];
        *(uint4*)(slo + o + 8) = *(const uint4*)&vl[8];
    }

    if (blockIdx.x < 256) {
        const float* xp = x + (size_t)blockIdx.x * 4096;
        unsigned short* xo = xb + (size_t)blockIdx.x * 4096;
        #pragma unroll
        for (int c = 0; c < 4; ++c) {
            int e = c * 1024 + tid * 4;
            float4 v = *(const float4*)(xp + e);
            unsigned short o4[4] = { f2bf(v.x), f2bf(v.y), f2bf(v.z), f2bf(v.w) };
            *(uint2*)(xo + e) = *(const uint2*)o4;
        }
    }
}

// ---- Kernel 2 (v9): BM=256 dbuf + global_load_lds(16B) staging, XOR-swizzled layout ----
// v7's schedule, but staging is direct HBM/L2 -> LDS (no VGPR round-trip, no ds_writes):
// each tile = 48 wave-chunks of 1KB (A 32, Bh 8, Bl 8) = 6 global_load_lds per wave.
// Linear LDS rows of 128B with XOR swizzle: source column (lane&7)*16 ^ ((row&7)*16)
// (involution), read index (gr*8) ^ ((row&7)*8) -- both sides swizzled (rule #21),
// bank profile identical to the old LSTRIDE=72 layout. Loaded bytes, fragment values,
// MFMA order (tiles asc, kk 0->32, hi->lo), part layout bit-identical -> absmax 0.0.
__global__ __launch_bounds__(512, 2) void k_gemm(const unsigned short* __restrict__ xb,
                                              const unsigned short* __restrict__ shi,
                                              const unsigned short* __restrict__ slo,
                                              float* __restrict__ part,
                                              int kchunk) {
    __shared__ __align__(16) unsigned short As[2][256 * 64];   // 64 KB
    __shared__ __align__(16) unsigned short Bh[2][64 * 64];    // 16 KB
    __shared__ __align__(16) unsigned short Bl[2][64 * 64];    // 16 KB
    const int tid = threadIdx.x;
    const int n0 = blockIdx.x * 64;
    const int kbase = blockIdx.z * kchunk;
    const int w = tid >> 6, lane = tid & 63;
    const int ln = lane & 15, quad = lane >> 4;
    const int wm = w >> 1, wn = w & 1;     // wave grid: 4 in M, 2 in N

    // pre-swizzled source column (shorts): lane covers 16B chunk (lane&7) of row-slot (lane>>3)
    const int sw = ((((lane & 7) * 16) ^ ((lane >> 3) * 16)) >> 1);   // 0..56, involution
    const int rsl = lane >> 3;                                        // row-slot 0..7

    f32x4 acc[4][2];
    #pragma unroll
    for (int mt = 0; mt < 4; ++mt)
        #pragma unroll
        for (int ct = 0; ct < 2; ++ct)
            #pragma unroll
            for (int rr = 0; rr < 4; ++rr) acc[mt][ct][rr] = 0.0f;

    const int nst = kchunk / BK;           // 16 steps

    // stage tile at k-offset kt into buffer sel: 6 async 1KB wave-chunks
    auto stage = [&](int sel, int kt) {
        #pragma unroll
        for (int j = 0; j < 4; ++j) {
            int ch = w * 4 + j;                       // A chunk 0..31
            int row = ch * 8 + rsl;                   // 0..255
            GLOAD16(xb + (size_t)row * Dd + kbase + kt + sw, &As[sel][ch * 512]);
        }
        int brow = w * 8 + rsl;                       // 0..63
        GLOAD16(shi + (size_t)(n0 + brow) * Dd + kbase + kt + sw, &Bh[sel][w * 512]);
        GLOAD16(slo + (size_t)(n0 + brow) * Dd + kbase + kt + sw, &Bl[sel][w * 512]);
    };

    stage(0, 0);                                      // prologue: tile 0 -> buf 0

    for (int t = 0; t < nst; ++t) {
        const int cur = t & 1;
        asm volatile("s_waitcnt vmcnt(0)" ::: "memory");   // buf[cur] loads landed
        __syncthreads();                                    // all waves' loads visible
        if (t + 1 < nst) stage(cur ^ 1, (t + 1) * BK);     // issue next tile (uniform branch)
        // ---- MFMA on tile t from buf[cur] ----
        const unsigned short* Ar = As[cur];
        const unsigned short* Hr = Bh[cur];
        const unsigned short* Lr = Bl[cur];
        #pragma unroll
        for (int kk = 0; kk < BK; kk += 32) {
            const int gr = (kk >> 3) + quad;
            const int sx = (gr * 8) ^ ((ln & 7) * 8);       // read-side swizzle (shorts)
            bf16x8 a[4];
            #pragma unroll
            for (int mt = 0; mt < 4; ++mt)
                a[mt] = *(const bf16x8*)&Ar[(wm * 64 + mt * 16 + ln) * 64 + sx];
            #pragma unroll
            for (int ct = 0; ct < 2; ++ct) {
                int rb = wn * 32 + ct * 16 + ln;
                bf16x8 bh = *(const bf16x8*)&Hr[rb * 64 + sx];
                bf16x8 bl = *(const bf16x8*)&Lr[rb * 64 + sx];
                #pragma unroll
                for (int mt = 0; mt < 4; ++mt) {
                    acc[mt][ct] = __builtin_amdgcn_mfma_f32_16x16x32_bf16(a[mt], bh, acc[mt][ct], 0, 0, 0);
                    acc[mt][ct] = __builtin_amdgcn_mfma_f32_16x16x32_bf16(a[mt], bl, acc[mt][ct], 0, 0, 0);
                }
            }
        }
    }
    float* prow = part + (size_t)blockIdx.z * (Bsz * Dd);
    #pragma unroll
    for (int mt = 0; mt < 4; ++mt)
        #pragma unroll
        for (int ct = 0; ct < 2; ++ct)
            #pragma unroll
            for (int rr = 0; rr < 4; ++rr) {
                int m = wm * 64 + mt * 16 + quad * 4 + rr;
                int n = n0 + wn * 32 + ct * 16 + ln;
                prow[(size_t)m * Dd + n] = acc[mt][ct][rr];
            }
}

// ---------------- block reduction helpers (256 threads = 4 waves) ----------------
__device__ __forceinline__ float block_max256(float v, float* redf) {
    #pragma unroll
    for (int off = 32; off; off >>= 1) v = fmaxf(v, __shfl_down(v, off));
    __syncthreads();
    if ((threadIdx.x & 63) == 0) redf[threadIdx.x >> 6] = v;
    __syncthreads();
    return fmaxf(fmaxf(redf[0], redf[1]), fmaxf(redf[2], redf[3]));
}
__device__ __forceinline__ float block_sum256(float v, float* redf) {
    #pragma unroll
    for (int off = 32; off; off >>= 1) v += __shfl_down(v, off);
    __syncthreads();
    if ((threadIdx.x & 63) == 0) redf[threadIdx.x >> 6] = v;
    __syncthreads();
    return (redf[0] + redf[1]) + (redf[2] + redf[3]);    // fixed order: deterministic
}

// ---- Kernel 3: per-row epilogue; launch_bounds(256,1) frees the VGPR budget ----
__global__ __launch_bounds__(256, 1) void k_epilogue(const float* __restrict__ x,
                                                  const float* __restrict__ W,
                                                  const int* __restrict__ radius_raw,
                                                  const float* __restrict__ gu,
                                                  const float* __restrict__ uvec,
                                                  const float* __restrict__ part,
                                                  const float* __restrict__ bias,
                                                  float* __restrict__ out,
                                                  int nsplit) {
    __shared__ float scx_s[Dd];        // 16 KB: sc values for flip-position lookups
    __shared__ float redf[2][4];       // double-buffered argmax combine
    __shared__ int   redi[2][4];
    __shared__ float redsum[4];
    __shared__ int   flips[MAXR];

    const int b = blockIdx.x;
    const int tid = threadIdx.x;
    const float* xrow  = x  + (size_t)b * Dd;
    const float* gurow = gu + (size_t)b * Dd;

    // ---- phase 1: grad = sum_z part[z] + bias (fixed order); sc/key in registers ----
    float4 g4[4], bs4[4], xv4[4], uu4[4];
    #pragma unroll
    for (int c = 0; c < 4; ++c) {
        int j = c * 1024 + tid * 4;
        g4[c]  = *(const float4*)(part + (size_t)b * Dd + j);      // z = 0
        bs4[c] = *(const float4*)(bias + j);
        xv4[c] = *(const float4*)(xrow + j);
        uu4[c] = *(const float4*)(gurow + j);
    }
    if (nsplit == 4) {
        // hand-unrolled: all 12 loads issue as one batch; add order ((p0+p1)+p2)+p3
        float4 p1[4], p2[4], p3[4];
        #pragma unroll
        for (int c = 0; c < 4; ++c) {
            int j = c * 1024 + tid * 4;
            p1[c] = *(const float4*)(part + (size_t)(1 * Bsz + b) * Dd + j);
            p2[c] = *(const float4*)(part + (size_t)(2 * Bsz + b) * Dd + j);
            p3[c] = *(const float4*)(part + (size_t)(3 * Bsz + b) * Dd + j);
        }
        #pragma unroll
        for (int c = 0; c < 4; ++c) {
            g4[c].x = ((g4[c].x + p1[c].x) + p2[c].x) + p3[c].x;
            g4[c].y = ((g4[c].y + p1[c].y) + p2[c].y) + p3[c].y;
            g4[c].z = ((g4[c].z + p1[c].z) + p2[c].z) + p3[c].z;
            g4[c].w = ((g4[c].w + p1[c].w) + p2[c].w) + p3[c].w;
        }
    } else {
        for (int z = 1; z < nsplit; ++z) {
            const float* pz = part + (size_t)z * (Bsz * Dd) + (size_t)b * Dd;
            #pragma unroll
            for (int c = 0; c < 4; ++c) {
                float4 a = *(const float4*)(pz + c * 1024 + tid * 4);
                g4[c].x += a.x; g4[c].y += a.y; g4[c].z += a.z; g4[c].w += a.w;
            }
        }
    }
    float sc[16], ky[16];
    float lmax = -FMAX;
    float lkey = -FMAX; int lidx = 0x7fffffff;
    #pragma unroll
    for (int c = 0; c < 4; ++c) {
        const float* gg = (const float*)&g4[c];
        const float* gc = (const float*)&bs4[c];
        const float* gx = (const float*)&xv4[c];
        const float* gup = (const float*)&uu4[c];
        #pragma unroll
        for (int e = 0; e < 4; ++e) {
            int r = c * 4 + e;
            float g = gg[e] + gc[e];
            float s = (1.0f - 2.0f * gx[e]) * g * 0.5f;
            float k = s - logf(-logf(fmaxf(gup[e], 1e-10f)));
            sc[r] = s;
            ky[r] = k;
            lmax = fmaxf(lmax, s);
            if (k > lkey) { lkey = k; lidx = c * 1024 + tid * 4 + e; }  // incr j: lowest-idx tie
        }
        *(float4*)&scx_s[c * 1024 + tid * 4] = *(const float4*)&sc[c * 4];
    }

    // ---- lse_x ----
    float mx = block_max256(lmax, redsum);
    float ls = 0.0f;
    #pragma unroll
    for (int r = 0; r < 16; ++r) ls += expf(sc[r] - mx);
    float sum_x = block_sum256(ls, redsum);
    float lse_x = mx + logf(sum_x);

    // ---- top-radius: tournament over register-cached per-thread maxima ----
    const int radius = radius_raw[b] + 1;             // [1, 15]
    unsigned removed = 0;
    for (int t = 0; t < radius; ++t) {
        float v = lkey; int idx = lidx;
        #pragma unroll
        for (int off = 32; off; off >>= 1) {
            float v2 = __shfl_down(v, off);
            int   i2 = __shfl_down(idx, off);
            if (v2 > v || (v2 == v && i2 < idx)) { v = v2; idx = i2; }
        }
        const int buf = t & 1;
        if ((tid & 63) == 0) { redf[buf][tid >> 6] = v; redi[buf][tid >> 6] = idx; }
        __syncthreads();
        float bv = redf[buf][0]; int bi = redi[buf][0];
        #pragma unroll
        for (int w2 = 1; w2 < 4; ++w2) {
            float v2 = redf[buf][w2]; int i2 = redi[buf][w2];
            if (v2 > bv || (v2 == bv && i2 < bi)) { bv = v2; bi = i2; }
        }
        if (tid == ((bi >> 2) & 255)) {       // owner: remove + rescan registers
            removed |= 1u << (((bi >> 10) << 2) | (bi & 3));
            lkey = -FMAX; lidx = 0x7fffffff;
            #pragma unroll
            for (int c = 0; c < 4; ++c)
                #pragma unroll
                for (int e = 0; e < 4; ++e) {
                    int r = c * 4 + e;
                    if (!(removed & (1u << r)) && ky[r] > lkey) {
                        lkey = ky[r]; lidx = c * 1024 + tid * 4 + e;
                    }
                }
        }
        if (tid == 0) flips[t] = bi;
    }
    __syncthreads();                           // flips[] visible to all

    // ---- lse_y via correction: sum_y = sum_x + sum_flips(e^{-sc-mx} - e^{+sc-mx}) ----
    float delta = 0.0f;
    if (tid < radius) {
        float sv = scx_s[flips[tid]];
        delta = expf(-sv - mx) - expf(sv - mx);
    }
    float sum_y = sum_x + block_sum256(delta, redsum);
    float lse_y = mx + logf(sum_y);

    // ---- pair term: 0.25 * sum_{p,q in flips} d_p d_q (W_pq + W_qp) ----
    float ts = 0.0f;
    for (int t = tid; t < radius * radius; t += 256) {
        int p = flips[t / radius], q = flips[t % radius];
        float dp = 1.0f - 2.0f * xrow[p];
        float dq = 1.0f - 2.0f * xrow[q];
        ts += 0.25f * dp * dq * (W[(size_t)p * Dd + q] + W[(size_t)q * Dd + p]);
    }
    float T = block_sum256(ts, redsum);

    float log_acc = fminf(T + lse_x - lse_y, 0.0f);
    int accepted = (expf(log_acc) > uvec[b]) ? 1 : 0;

    // ---- output: x everywhere (from registers), flips overwritten iff accepted ----
    float* orow = out + (size_t)b * Dd;
    #pragma unroll
    for (int c = 0; c < 4; ++c)
        *(float4*)(orow + c * 1024 + tid * 4) = xv4[c];
    __syncthreads();
    if (accepted && tid < radius) {
        int p = flips[tid];
        orow[p] = 1.0f - xrow[p];
    }
}

extern "C" void kernel_launch(void* const* d_in, const int* in_sizes, int n_in,
                              void* d_out, int out_size, void* d_ws, size_t ws_size,
                              hipStream_t stream) {
    const float* x          = (const float*)d_in[0];
    const float* W          = (const float*)d_in[1];
    const float* bias       = (const float*)d_in[2];
    const int*   radius_raw = (const int*)d_in[3];
    const float* gu         = (const float*)d_in[4];
    const float* u          = (const float*)d_in[5];
    float* out = (float*)d_out;

    // ws: shi 33.55 MB | slo 33.55 MB | xb 2.1 MB | part nsplit*4.19 MB
    unsigned short* shi = (unsigned short*)d_ws;
    unsigned short* slo = shi + (size_t)Dd * Dd;
    unsigned short* xb  = slo + (size_t)Dd * Dd;
    float*          prt = (float*)(xb + (size_t)Bsz * Dd);

    // nsplit=4 (champion K-partition preserved); ws_size constant across calls => graph-safe.
    const size_t fixed = (size_t)2 * Dd * Dd * 2 + (size_t)Bsz * Dd * 2;
    const int nsplit = (ws_size >= fixed + (size_t)4 * Bsz * Dd * 4) ? 4 : 2;
    const int kchunk = Dd / nsplit;

    k_ssym<<<2080, 256, 0, stream>>>(W, x, shi, slo, xb);
    k_gemm<<<dim3(64, 1, nsplit), 512, 0, stream>>>(xb, shi, slo, prt, kchunk);
    k_epilogue<<<Bsz, 256, 0, stream>>>(x, W, radius_raw, gu, u, prt, bias, out, nsplit);
}

// Round 10
// 165.937 us; speedup vs baseline: 1.0263x; 1.0263x over previous
//
#include <hip/hip_runtime.h>

#define Bsz 256
#define Dd  4096
#define MAXR 15
#define FMAX 3.402823466e+38f
#define BK 64
#define LSTRIDE 72              // 9 granules (odd): conflict-free phases, 16B-aligned rows

typedef short bf16x8 __attribute__((ext_vector_type(8)));
typedef float f32x4  __attribute__((ext_vector_type(4)));

__device__ __forceinline__ unsigned short f2bf(float f) {
    unsigned int u = __float_as_uint(f);
    unsigned int r = (u + 0x7fffu + ((u >> 16) & 1u)) >> 16;   // RNE
    return (unsigned short)r;
}
__device__ __forceinline__ float bf2f(unsigned short h) {
    return __uint_as_float(((unsigned int)h) << 16);
}

// ---- Kernel 1: S = 0.5*(W+W^T) -> bf16 hi/lo (triangle-paired) + fused x->bf16 ----
__global__ __launch_bounds__(256) void k_ssym(const float* __restrict__ W,
                                              const float* __restrict__ x,
                                              unsigned short* __restrict__ shi,
                                              unsigned short* __restrict__ slo,
                                              unsigned short* __restrict__ xb) {
    __shared__ float t1[64][68];
    __shared__ float t2[64][68];
    int bid = blockIdx.x;
    int bi = 0;
    while (bid >= 64 - bi) { bid -= 64 - bi; ++bi; }
    const int bj = bi + bid;
    const int i0 = bi * 64, j0 = bj * 64;
    const int tid = threadIdx.x;

    #pragma unroll
    for (int sb = 0; sb < 4; ++sb) {
        int s = sb * 256 + tid;
        int r = s >> 4, q = (s & 15) * 4;
        *(float4*)&t1[r][q] = *(const float4*)(W + (size_t)(i0 + r) * Dd + j0 + q);
        *(float4*)&t2[r][q] = *(const float4*)(W + (size_t)(j0 + r) * Dd + i0 + q);
    }
    __syncthreads();

    const int r = tid >> 2, c0 = (tid & 3) * 16;
    {   // S_ij[r][c] = 0.5*(t1[r][c] + t2[c][r])
        unsigned short vh[16], vl[16];
        #pragma unroll
        for (int k = 0; k < 16; ++k) {
            float s = 0.5f * (t1[r][c0 + k] + t2[c0 + k][r]);
            vh[k] = f2bf(s);
            vl[k] = f2bf(s - bf2f(vh[k]));
        }
        size_t o = (size_t)(i0 + r) * Dd + j0 + c0;
        *(uint4*)(shi + o) = *(const uint4*)&vh[0];
        *(uint4*)(shi + o + 8) = *(const uint4*)&vh[8];
        *(uint4*)(slo + o) = *(const uint4*)&vl[0];
        *(uint4*)(slo + o + 8) = *(const uint4*)&vl[8];
    }
    if (bi != bj) {   // S_ji[r][c] = 0.5*(t2[r][c] + t1[c][r])
        unsigned short vh[16], vl[16];
        #pragma unroll
        for (int k = 0; k < 16; ++k) {
            float s = 0.5f * (t2[r][c0 + k] + t1[c0 + k][r]);
            vh[k] = f2bf(s);
            vl[k] = f2bf(s - bf2f(vh[k]));
        }
        size_t o = (size_t)(j0 + r) * Dd + i0 + c0;
        *(uint4*)(shi + o) = *(const uint4*)&vh[0];
        *(uint4*)(shi + o + 8) = *(const uint4*)&vh[8];
        *(uint4*)(slo + o) = *(const uint4*)&vl[0];
        *(uint4*)(slo + o + 8) = *(const uint4*)&vl[8];
    }

    if (blockIdx.x < 256) {
        const float* xp = x + (size_t)blockIdx.x * 4096;
        unsigned short* xo = xb + (size_t)blockIdx.x * 4096;
        #pragma unroll
        for (int c = 0; c < 4; ++c) {
            int e = c * 1024 + tid * 4;
            float4 v = *(const float4*)(xp + e);
            unsigned short o4[4] = { f2bf(v.x), f2bf(v.y), f2bf(v.z), f2bf(v.w) };
            *(uint2*)(xo + e) = *(const uint2*)o4;
        }
    }
}

// ---- Kernel 2 (v7 champion, restored): BM=256 dbuf single-barrier ----
// Best measured (167.3us total). B streamed from HBM exactly once; tile t+1 staged
// into buf[(t+1)&1] while MFMA consumes tile t from buf[t&1] -> one barrier/step.
// Lever sweep post-mortem (rounds 2-9): fusion -22..-49us, occupancy 2x/4x -0/-27,
// lgkm-only barrier +-0, global_load_lds+swizzle -3 => this structure is the plateau.
// Staging values, per-acc MFMA k-sequence (tiles asc, kk 0->32, hi->lo), part layout
// bit-identical to the round-1 champion -> absmax 0.0.
__global__ __launch_bounds__(512, 2) void k_gemm(const unsigned short* __restrict__ xb,
                                              const unsigned short* __restrict__ shi,
                                              const unsigned short* __restrict__ slo,
                                              float* __restrict__ part,
                                              int kchunk) {
    __shared__ __align__(16) unsigned short As[2][256 * LSTRIDE];  // 73.7 KB
    __shared__ __align__(16) unsigned short Bh[2][64 * LSTRIDE];   // 18.4 KB
    __shared__ __align__(16) unsigned short Bl[2][64 * LSTRIDE];   // 18.4 KB
    const int tid = threadIdx.x;
    const int n0 = blockIdx.x * 64;
    const int kbase = blockIdx.z * kchunk;
    const int w = tid >> 6, lane = tid & 63;
    const int ln = lane & 15, quad = lane >> 4;
    const int wm = w >> 1, wn = w & 1;     // wave grid: 4 in M, 2 in N

    // staging: A = 256 rows x 8 granules (4/thread); B = 64 x 8 (1/thread each)
    unsigned ga[4]; int la[4];
    #pragma unroll
    for (int j = 0; j < 4; ++j) {
        int s = tid + j * 512;
        int r = s >> 3, g = s & 7;
        ga[j] = (unsigned)(r * Dd + kbase + g * 8);
        la[j] = r * LSTRIDE + g * 8;
    }
    const int rb2 = tid >> 3, gb2 = tid & 7;
    const unsigned gb = (unsigned)((n0 + rb2) * Dd + kbase + gb2 * 8);
    const int lb = rb2 * LSTRIDE + gb2 * 8;

    f32x4 acc[4][2];
    #pragma unroll
    for (int mt = 0; mt < 4; ++mt)
        #pragma unroll
        for (int ct = 0; ct < 2; ++ct)
            #pragma unroll
            for (int rr = 0; rr < 4; ++rr) acc[mt][ct][rr] = 0.0f;

    const int nst = kchunk / BK;           // 16 steps

    // wr-regs hold the tile pending its LDS write
    bf16x8 va[4], vh, vl;
    // prologue: load tile 0, write buf[0], then load tile 1 (in flight over step 0 MFMA)
    #pragma unroll
    for (int j = 0; j < 4; ++j) va[j] = *(const bf16x8*)(xb  + ga[j]);
    vh = *(const bf16x8*)(shi + gb);
    vl = *(const bf16x8*)(slo + gb);
    #pragma unroll
    for (int j = 0; j < 4; ++j) *(bf16x8*)&As[0][la[j]] = va[j];
    *(bf16x8*)&Bh[0][lb] = vh;
    *(bf16x8*)&Bl[0][lb] = vl;
    {
        int ks = (nst > 1) ? BK : 0;
        #pragma unroll
        for (int j = 0; j < 4; ++j) va[j] = *(const bf16x8*)(xb  + ga[j] + ks);
        vh = *(const bf16x8*)(shi + gb + ks);
        vl = *(const bf16x8*)(slo + gb + ks);
    }

    for (int t = 0; t < nst; ++t) {
        const int cur = t & 1;
        __syncthreads();   // buf[cur] (written at t-1) visible; MFMA(t-1) done with buf[cur^1]
        // ---- stage tile t+1 into buf[cur^1] (consumed by MFMA at t+1) ----
        #pragma unroll
        for (int j = 0; j < 4; ++j) *(bf16x8*)&As[cur ^ 1][la[j]] = va[j];
        *(bf16x8*)&Bh[cur ^ 1][lb] = vh;
        *(bf16x8*)&Bl[cur ^ 1][lb] = vl;
        // ---- issue loads for tile t+2 (one full MFMA phase to land) ----
        {
            int kn = (t + 2) * BK;
            int ks = (kn < kchunk) ? kn : 0;   // wrap: harmless garbage, never consumed
            #pragma unroll
            for (int j = 0; j < 4; ++j) va[j] = *(const bf16x8*)(xb  + ga[j] + ks);
            vh = *(const bf16x8*)(shi + gb + ks);
            vl = *(const bf16x8*)(slo + gb + ks);
        }
        // ---- MFMA on tile t from buf[cur] (independent of this step's writes) ----
        const unsigned short* Ar = As[cur];
        const unsigned short* Hr = Bh[cur];
        const unsigned short* Lr = Bl[cur];
        #pragma unroll
        for (int kk = 0; kk < BK; kk += 32) {
            const int gr = (kk >> 3) + quad;
            bf16x8 a[4];
            #pragma unroll
            for (int mt = 0; mt < 4; ++mt)
                a[mt] = *(const bf16x8*)&Ar[(wm * 64 + mt * 16 + ln) * LSTRIDE + gr * 8];
            #pragma unroll
            for (int ct = 0; ct < 2; ++ct) {
                int rb = wn * 32 + ct * 16 + ln;
                bf16x8 bh = *(const bf16x8*)&Hr[rb * LSTRIDE + gr * 8];
                bf16x8 bl = *(const bf16x8*)&Lr[rb * LSTRIDE + gr * 8];
                #pragma unroll
                for (int mt = 0; mt < 4; ++mt) {
                    acc[mt][ct] = __builtin_amdgcn_mfma_f32_16x16x32_bf16(a[mt], bh, acc[mt][ct], 0, 0, 0);
                    acc[mt][ct] = __builtin_amdgcn_mfma_f32_16x16x32_bf16(a[mt], bl, acc[mt][ct], 0, 0, 0);
                }
            }
        }
    }
    float* prow = part + (size_t)blockIdx.z * (Bsz * Dd);
    #pragma unroll
    for (int mt = 0; mt < 4; ++mt)
        #pragma unroll
        for (int ct = 0; ct < 2; ++ct)
            #pragma unroll
            for (int rr = 0; rr < 4; ++rr) {
                int m = wm * 64 + mt * 16 + quad * 4 + rr;
                int n = n0 + wn * 32 + ct * 16 + ln;
                prow[(size_t)m * Dd + n] = acc[mt][ct][rr];
            }
}

// ---------------- block reduction helpers (256 threads = 4 waves) ----------------
__device__ __forceinline__ float block_max256(float v, float* redf) {
    #pragma unroll
    for (int off = 32; off; off >>= 1) v = fmaxf(v, __shfl_down(v, off));
    __syncthreads();
    if ((threadIdx.x & 63) == 0) redf[threadIdx.x >> 6] = v;
    __syncthreads();
    return fmaxf(fmaxf(redf[0], redf[1]), fmaxf(redf[2], redf[3]));
}
__device__ __forceinline__ float block_sum256(float v, float* redf) {
    #pragma unroll
    for (int off = 32; off; off >>= 1) v += __shfl_down(v, off);
    __syncthreads();
    if ((threadIdx.x & 63) == 0) redf[threadIdx.x >> 6] = v;
    __syncthreads();
    return (redf[0] + redf[1]) + (redf[2] + redf[3]);    // fixed order: deterministic
}

// ---- Kernel 3: per-row epilogue; launch_bounds(256,1) frees the VGPR budget ----
__global__ __launch_bounds__(256, 1) void k_epilogue(const float* __restrict__ x,
                                                  const float* __restrict__ W,
                                                  const int* __restrict__ radius_raw,
                                                  const float* __restrict__ gu,
                                                  const float* __restrict__ uvec,
                                                  const float* __restrict__ part,
                                                  const float* __restrict__ bias,
                                                  float* __restrict__ out,
                                                  int nsplit) {
    __shared__ float scx_s[Dd];        // 16 KB: sc values for flip-position lookups
    __shared__ float redf[2][4];       // double-buffered argmax combine
    __shared__ int   redi[2][4];
    __shared__ float redsum[4];
    __shared__ int   flips[MAXR];

    const int b = blockIdx.x;
    const int tid = threadIdx.x;
    const float* xrow  = x  + (size_t)b * Dd;
    const float* gurow = gu + (size_t)b * Dd;

    // ---- phase 1: grad = sum_z part[z] + bias (fixed order); sc/key in registers ----
    float4 g4[4], bs4[4], xv4[4], uu4[4];
    #pragma unroll
    for (int c = 0; c < 4; ++c) {
        int j = c * 1024 + tid * 4;
        g4[c]  = *(const float4*)(part + (size_t)b * Dd + j);      // z = 0
        bs4[c] = *(const float4*)(bias + j);
        xv4[c] = *(const float4*)(xrow + j);
        uu4[c] = *(const float4*)(gurow + j);
    }
    if (nsplit == 4) {
        // hand-unrolled: all 12 loads issue as one batch; add order ((p0+p1)+p2)+p3
        float4 p1[4], p2[4], p3[4];
        #pragma unroll
        for (int c = 0; c < 4; ++c) {
            int j = c * 1024 + tid * 4;
            p1[c] = *(const float4*)(part + (size_t)(1 * Bsz + b) * Dd + j);
            p2[c] = *(const float4*)(part + (size_t)(2 * Bsz + b) * Dd + j);
            p3[c] = *(const float4*)(part + (size_t)(3 * Bsz + b) * Dd + j);
        }
        #pragma unroll
        for (int c = 0; c < 4; ++c) {
            g4[c].x = ((g4[c].x + p1[c].x) + p2[c].x) + p3[c].x;
            g4[c].y = ((g4[c].y + p1[c].y) + p2[c].y) + p3[c].y;
            g4[c].z = ((g4[c].z + p1[c].z) + p2[c].z) + p3[c].z;
            g4[c].w = ((g4[c].w + p1[c].w) + p2[c].w) + p3[c].w;
        }
    } else {
        for (int z = 1; z < nsplit; ++z) {
            const float* pz = part + (size_t)z * (Bsz * Dd) + (size_t)b * Dd;
            #pragma unroll
            for (int c = 0; c < 4; ++c) {
                float4 a = *(const float4*)(pz + c * 1024 + tid * 4);
                g4[c].x += a.x; g4[c].y += a.y; g4[c].z += a.z; g4[c].w += a.w;
            }
        }
    }
    float sc[16], ky[16];
    float lmax = -FMAX;
    float lkey = -FMAX; int lidx = 0x7fffffff;
    #pragma unroll
    for (int c = 0; c < 4; ++c) {
        const float* gg = (const float*)&g4[c];
        const float* gc = (const float*)&bs4[c];
        const float* gx = (const float*)&xv4[c];
        const float* gup = (const float*)&uu4[c];
        #pragma unroll
        for (int e = 0; e < 4; ++e) {
            int r = c * 4 + e;
            float g = gg[e] + gc[e];
            float s = (1.0f - 2.0f * gx[e]) * g * 0.5f;
            float k = s - logf(-logf(fmaxf(gup[e], 1e-10f)));
            sc[r] = s;
            ky[r] = k;
            lmax = fmaxf(lmax, s);
            if (k > lkey) { lkey = k; lidx = c * 1024 + tid * 4 + e; }  // incr j: lowest-idx tie
        }
        *(float4*)&scx_s[c * 1024 + tid * 4] = *(const float4*)&sc[c * 4];
    }

    // ---- lse_x ----
    float mx = block_max256(lmax, redsum);
    float ls = 0.0f;
    #pragma unroll
    for (int r = 0; r < 16; ++r) ls += expf(sc[r] - mx);
    float sum_x = block_sum256(ls, redsum);
    float lse_x = mx + logf(sum_x);

    // ---- top-radius: tournament over register-cached per-thread maxima ----
    const int radius = radius_raw[b] + 1;             // [1, 15]
    unsigned removed = 0;
    for (int t = 0; t < radius; ++t) {
        float v = lkey; int idx = lidx;
        #pragma unroll
        for (int off = 32; off; off >>= 1) {
            float v2 = __shfl_down(v, off);
            int   i2 = __shfl_down(idx, off);
            if (v2 > v || (v2 == v && i2 < idx)) { v = v2; idx = i2; }
        }
        const int buf = t & 1;
        if ((tid & 63) == 0) { redf[buf][tid >> 6] = v; redi[buf][tid >> 6] = idx; }
        __syncthreads();
        float bv = redf[buf][0]; int bi = redi[buf][0];
        #pragma unroll
        for (int w2 = 1; w2 < 4; ++w2) {
            float v2 = redf[buf][w2]; int i2 = redi[buf][w2];
            if (v2 > bv || (v2 == bv && i2 < bi)) { bv = v2; bi = i2; }
        }
        if (tid == ((bi >> 2) & 255)) {       // owner: remove + rescan registers
            removed |= 1u << (((bi >> 10) << 2) | (bi & 3));
            lkey = -FMAX; lidx = 0x7fffffff;
            #pragma unroll
            for (int c = 0; c < 4; ++c)
                #pragma unroll
                for (int e = 0; e < 4; ++e) {
                    int r = c * 4 + e;
                    if (!(removed & (1u << r)) && ky[r] > lkey) {
                        lkey = ky[r]; lidx = c * 1024 + tid * 4 + e;
                    }
                }
        }
        if (tid == 0) flips[t] = bi;
    }
    __syncthreads();                           // flips[] visible to all

    // ---- lse_y via correction: sum_y = sum_x + sum_flips(e^{-sc-mx} - e^{+sc-mx}) ----
    float delta = 0.0f;
    if (tid < radius) {
        float sv = scx_s[flips[tid]];
        delta = expf(-sv - mx) - expf(sv - mx);
    }
    float sum_y = sum_x + block_sum256(delta, redsum);
    float lse_y = mx + logf(sum_y);

    // ---- pair term: 0.25 * sum_{p,q in flips} d_p d_q (W_pq + W_qp) ----
    float ts = 0.0f;
    for (int t = tid; t < radius * radius; t += 256) {
        int p = flips[t / radius], q = flips[t % radius];
        float dp = 1.0f - 2.0f * xrow[p];
        float dq = 1.0f - 2.0f * xrow[q];
        ts += 0.25f * dp * dq * (W[(size_t)p * Dd + q] + W[(size_t)q * Dd + p]);
    }
    float T = block_sum256(ts, redsum);

    float log_acc = fminf(T + lse_x - lse_y, 0.0f);
    int accepted = (expf(log_acc) > uvec[b]) ? 1 : 0;

    // ---- output: x everywhere (from registers), flips overwritten iff accepted ----
    float* orow = out + (size_t)b * Dd;
    #pragma unroll
    for (int c = 0; c < 4; ++c)
        *(float4*)(orow + c * 1024 + tid * 4) = xv4[c];
    __syncthreads();
    if (accepted && tid < radius) {
        int p = flips[tid];
        orow[p] = 1.0f - xrow[p];
    }
}

extern "C" void kernel_launch(void* const* d_in, const int* in_sizes, int n_in,
                              void* d_out, int out_size, void* d_ws, size_t ws_size,
                              hipStream_t stream) {
    const float* x          = (const float*)d_in[0];
    const float* W          = (const float*)d_in[1];
    const float* bias       = (const float*)d_in[2];
    const int*   radius_raw = (const int*)d_in[3];
    const float* gu         = (const float*)d_in[4];
    const float* u          = (const float*)d_in[5];
    float* out = (float*)d_out;

    // ws: shi 33.55 MB | slo 33.55 MB | xb 2.1 MB | part nsplit*4.19 MB
    unsigned short* shi = (unsigned short*)d_ws;
    unsigned short* slo = shi + (size_t)Dd * Dd;
    unsigned short* xb  = slo + (size_t)Dd * Dd;
    float*          prt = (float*)(xb + (size_t)Bsz * Dd);

    // nsplit=4 (champion K-partition preserved); ws_size constant across calls => graph-safe.
    const size_t fixed = (size_t)2 * Dd * Dd * 2 + (size_t)Bsz * Dd * 2;
    const int nsplit = (ws_size >= fixed + (size_t)4 * Bsz * Dd * 4) ? 4 : 2;
    const int kchunk = Dd / nsplit;

    k_ssym<<<2080, 256, 0, stream>>>(W, x, shi, slo, xb);
    k_gemm<<<dim3(64, 1, nsplit), 512, 0, stream>>>(xb, shi, slo, prt, kchunk);
    k_epilogue<<<Bsz, 256, 0, stream>>>(x, W, radius_raw, gu, u, prt, bias, out, nsplit);
}